// Round 1
// baseline (1845.317 us; speedup 1.0000x reference)
//
#include <hip/hip_runtime.h>
#include <hip/hip_bf16.h>
#include <cstdint>

#define TSTEPS  128
#define INDIM   256
#define HIDDEN  64
#define FREQN   10
#define NOUT    16
#define XSTRIDE 272   // padded col stride of xproj: [i:0][ste:64][c:128][o:192][fre:256..265]

// ---------------------------------------------------------------------------
// GEMM: xproj[:, seg] = g1row @ W_seg + b_seg   (four 64-col segments)
// A rows are mapped through the chunk transform: rp = b*TC + tt -> grow = b*128 + ci*TC + tt
// ---------------------------------------------------------------------------
__global__ __launch_bounds__(256)
void gemm_xw64(const float* __restrict__ A,
               const float* __restrict__ W0, const float* __restrict__ W1,
               const float* __restrict__ W2, const float* __restrict__ W3,
               const float* __restrict__ b0, const float* __restrict__ b1,
               const float* __restrict__ b2, const float* __restrict__ b3,
               float* __restrict__ outp, int ci, int tclog)
{
    __shared__ float As[32][132];   // transposed A tile: As[k][row], stride 132 (16B aligned, conflict-light)
    __shared__ float Bs[32][68];
    const int tid = threadIdx.x;
    const int bm  = blockIdx.x;
    const float* W; const float* bb;
    switch (blockIdx.y) {
        case 0:  W = W0; bb = b0; break;
        case 1:  W = W1; bb = b1; break;
        case 2:  W = W2; bb = b2; break;
        default: W = W3; bb = b3; break;
    }
    const int col0 = blockIdx.y * 64;
    const int tx = tid & 15, ty = tid >> 4;       // micro-tile: 8 rows x 4 cols
    const int lr = tid >> 3, lk4 = (tid & 7) * 4; // A-tile load mapping
    const int tcm = (1 << tclog) - 1;

    float acc[8][4];
    #pragma unroll
    for (int i = 0; i < 8; ++i)
        #pragma unroll
        for (int j = 0; j < 4; ++j) acc[i][j] = 0.f;

    for (int k0 = 0; k0 < INDIM; k0 += 32) {
        #pragma unroll
        for (int p = 0; p < 4; ++p) {
            int r  = lr + p * 32;
            int rp = bm * 128 + r;
            int grow = ((rp >> tclog) << 7) + (ci << tclog) + (rp & tcm);
            float4 v = *reinterpret_cast<const float4*>(A + (size_t)grow * INDIM + k0 + lk4);
            As[lk4 + 0][r] = v.x; As[lk4 + 1][r] = v.y;
            As[lk4 + 2][r] = v.z; As[lk4 + 3][r] = v.w;
        }
        #pragma unroll
        for (int p = 0; p < 2; ++p) {
            int kr = (tid >> 4) + p * 16;
            int c4 = (tid & 15) * 4;
            float4 v = *reinterpret_cast<const float4*>(W + (size_t)(k0 + kr) * 64 + c4);
            *reinterpret_cast<float4*>(&Bs[kr][c4]) = v;
        }
        __syncthreads();
        #pragma unroll
        for (int kk = 0; kk < 32; ++kk) {
            float4 a0 = *reinterpret_cast<const float4*>(&As[kk][ty * 8]);
            float4 a1 = *reinterpret_cast<const float4*>(&As[kk][ty * 8 + 4]);
            float4 b  = *reinterpret_cast<const float4*>(&Bs[kk][tx * 4]);
            float av[8] = {a0.x, a0.y, a0.z, a0.w, a1.x, a1.y, a1.z, a1.w};
            float bv[4] = {b.x, b.y, b.z, b.w};
            #pragma unroll
            for (int i = 0; i < 8; ++i)
                #pragma unroll
                for (int j = 0; j < 4; ++j)
                    acc[i][j] = __fmaf_rn(av[i], bv[j], acc[i][j]);
        }
        __syncthreads();
    }
    #pragma unroll
    for (int i = 0; i < 8; ++i) {
        int rp = bm * 128 + ty * 8 + i;
        #pragma unroll
        for (int j = 0; j < 4; ++j) {
            int c = tx * 4 + j;
            outp[(size_t)rp * XSTRIDE + col0 + c] = acc[i][j] + bb[c];
        }
    }
}

// fre segment: 10 output cols; micro-tile 8 rows x 1 col
__global__ __launch_bounds__(256)
void gemm_xwfre(const float* __restrict__ A, const float* __restrict__ W,
                const float* __restrict__ bb, float* __restrict__ outp,
                int ci, int tclog)
{
    __shared__ float As[32][132];
    __shared__ float Bs[32][16];
    const int tid = threadIdx.x;
    const int bm  = blockIdx.x;
    const int tx = tid & 15, ty = tid >> 4;
    const int lr = tid >> 3, lk4 = (tid & 7) * 4;
    const int tcm = (1 << tclog) - 1;

    float acc[8];
    #pragma unroll
    for (int i = 0; i < 8; ++i) acc[i] = 0.f;

    for (int k0 = 0; k0 < INDIM; k0 += 32) {
        #pragma unroll
        for (int p = 0; p < 4; ++p) {
            int r  = lr + p * 32;
            int rp = bm * 128 + r;
            int grow = ((rp >> tclog) << 7) + (ci << tclog) + (rp & tcm);
            float4 v = *reinterpret_cast<const float4*>(A + (size_t)grow * INDIM + k0 + lk4);
            As[lk4 + 0][r] = v.x; As[lk4 + 1][r] = v.y;
            As[lk4 + 2][r] = v.z; As[lk4 + 3][r] = v.w;
        }
        #pragma unroll
        for (int p = 0; p < 2; ++p) {
            int idx = p * 256 + tid;
            int kr = idx >> 4, c = idx & 15;
            Bs[kr][c] = (c < FREQN) ? W[(size_t)(k0 + kr) * FREQN + c] : 0.f;
        }
        __syncthreads();
        #pragma unroll
        for (int kk = 0; kk < 32; ++kk) {
            float4 a0 = *reinterpret_cast<const float4*>(&As[kk][ty * 8]);
            float4 a1 = *reinterpret_cast<const float4*>(&As[kk][ty * 8 + 4]);
            float b = Bs[kk][tx];
            float av[8] = {a0.x, a0.y, a0.z, a0.w, a1.x, a1.y, a1.z, a1.w};
            #pragma unroll
            for (int i = 0; i < 8; ++i) acc[i] = __fmaf_rn(av[i], b, acc[i]);
        }
        __syncthreads();
    }
    if (tx < FREQN) {
        #pragma unroll
        for (int i = 0; i < 8; ++i) {
            int rp = bm * 128 + ty * 8 + i;
            outp[(size_t)rp * XSTRIDE + 256 + tx] = acc[i] + bb[tx];
        }
    }
}

// ---------------------------------------------------------------------------
// cos/sin table: replicates reference fp32 rounding exactly:
//   omega = fl( fl(TWO_PI_f32 * time) * fl(j/10) ),  time = t+1
// ---------------------------------------------------------------------------
__global__ void cstab_kernel(float2* __restrict__ tab)
{
    int idx = blockIdx.x * 256 + threadIdx.x;
    if (idx >= TSTEPS * FREQN) return;
    int t = idx / FREQN, j = idx - t * FREQN;
    float time = (float)(t + 1);
    float om = (6.28318530717958647692f * time) * ((float)j / 10.0f);
    float s, c;
    sincosf(om, &s, &c);
    tab[idx] = make_float2(c, s);
}

// ---------------------------------------------------------------------------
// Recurrent kernel: one wave per batch row, lane = hidden dim.
// LDS: Upk[k][h] = float4{U_i,U_ste,U_c,U_o}[k][h]  (64KB) + U_fre (2.5KB)
// ---------------------------------------------------------------------------
__device__ __forceinline__ float rdlane(float v, int l) {
    return __int_as_float(__builtin_amdgcn_readlane(__float_as_int(v), l));
}
__device__ __forceinline__ float hsig(float x) {
    return fminf(fmaxf(__fmaf_rn(x, (1.0f / 6.0f), 0.5f), 0.0f), 1.0f);
}
__device__ __forceinline__ float tanh_f(float x) {
    float e = __expf(2.0f * x);      // inf for large x -> 1-2/inf = 1; 0 for very neg -> -1
    return 1.0f - 2.0f / (e + 1.0f);
}

__global__ __launch_bounds__(256)
void rec_kernel(const float* __restrict__ xproj,
                const float* __restrict__ Ui, const float* __restrict__ Us,
                const float* __restrict__ Uc, const float* __restrict__ Uo,
                const float* __restrict__ Ufre, const float* __restrict__ Ua,
                const float* __restrict__ ba,
                const float2* __restrict__ csTab,
                float* __restrict__ state,
                const float* __restrict__ Wp, const float* __restrict__ bp,
                const float* __restrict__ fcw, const float* __restrict__ fcb,
                float* __restrict__ outv,
                int ci, int TC, int nchunks)
{
    extern __shared__ float smem[];                 // 4096*4 + 640 floats = 68096 B
    float4* Upk = reinterpret_cast<float4*>(smem);
    float*  Ufr = smem + 16384;
    const int tid = threadIdx.x;

    for (int idx = tid; idx < 4096; idx += 256)
        Upk[idx] = make_float4(Ui[idx], Us[idx], Uc[idx], Uo[idx]);
    for (int idx = tid; idx < 640; idx += 256) Ufr[idx] = Ufre[idx];
    __syncthreads();

    const int lane = tid & 63;
    const int w    = tid >> 6;
    const int row  = blockIdx.x * 4 + w;
    const int jc   = (lane < FREQN) ? lane : (FREQN - 1);

    float h, Sre[FREQN], Sim[FREQN];
    if (ci == 0) {
        h = 0.f;
        #pragma unroll
        for (int j = 0; j < FREQN; ++j) { Sre[j] = 0.f; Sim[j] = 0.f; }
    } else {
        h = state[row * 64 + lane];
        #pragma unroll
        for (int j = 0; j < FREQN; ++j) {
            Sre[j] = state[65536 + j * 65536 + row * 64 + lane];
            Sim[j] = state[65536 + 655360 + j * 65536 + row * 64 + lane];
        }
    }
    const float ba_l = ba[lane];
    float sua[FREQN];
    #pragma unroll
    for (int j = 0; j < FREQN; ++j) sua[j] = Ua[j];   // uniform -> s_load

    const float* xbase = xproj + (size_t)row * TC * XSTRIDE;
    // software prefetch one step ahead
    float xi = xbase[lane], xs = xbase[64 + lane], xc = xbase[128 + lane];
    float xo = xbase[192 + lane], xf = xbase[256 + jc];
    float2 cv = csTab[(ci * TC) * FREQN + jc];

    for (int tt = 0; tt < TC; ++tt) {
        float cxi = xi, cxs = xs, cxc = xc, cxo = xo, cxf = xf;
        float2 ccv = cv;
        if (tt + 1 < TC) {
            const float* b = xbase + (size_t)(tt + 1) * XSTRIDE;
            xi = b[lane]; xs = b[64 + lane]; xc = b[128 + lane];
            xo = b[192 + lane]; xf = b[256 + jc];
            cv = csTab[(ci * TC + tt + 1) * FREQN + jc];
        }
        float ai = 0.f, as_ = 0.f, ac = 0.f, ao = 0.f, af = 0.f;
        #pragma unroll
        for (int k = 0; k < HIDDEN; ++k) {
            float hk = rdlane(h, k);                 // v_readlane (const k)
            float4 u = Upk[k * 64 + lane];           // ds_read_b128
            float uf = Ufr[k * FREQN + jc];
            ai  = __fmaf_rn(hk, u.x, ai);
            as_ = __fmaf_rn(hk, u.y, as_);
            ac  = __fmaf_rn(hk, u.z, ac);
            ao  = __fmaf_rn(hk, u.w, ao);
            af  = __fmaf_rn(hk, uf, af);
        }
        float gi = hsig(cxi + ai);
        float gs = hsig(cxs + as_);
        float gc = gi * tanh_f(cxc + ac);
        float go = hsig(cxo + ao);
        float pf = cxf + af;                         // valid on lanes 0..9
        float aacc = 0.f;
        #pragma unroll
        for (int j = 0; j < FREQN; ++j) {
            float fre_j = hsig(rdlane(pf, j));
            float cj = rdlane(ccv.x, j);
            float sj = rdlane(ccv.y, j);
            float fj = gs * fre_j;
            Sre[j] = __fmaf_rn(fj, Sre[j], gc * cj);
            Sim[j] = __fmaf_rn(fj, Sim[j], gc * sj);
            float Aj = __fmaf_rn(Sre[j], Sre[j], Sim[j] * Sim[j]);
            aacc = __fmaf_rn(Aj, sua[j], aacc);
        }
        float ag = tanh_f(aacc + ba_l);
        h = go * ag;
    }

    if (ci == nchunks - 1) {
        // out[row] = fc_b + sum_o fc_w[o]*b_p[o] + sum_k h[k] * (W_p[k,:]@fc_w)
        float wef = 0.f;
        #pragma unroll
        for (int o = 0; o < NOUT; ++o)
            wef = __fmaf_rn(Wp[lane * NOUT + o], fcw[o], wef);
        float v = h * wef;
        #pragma unroll
        for (int off = 32; off > 0; off >>= 1) v += __shfl_xor(v, off, 64);
        if (lane == 0) {
            float cb = fcb[0];
            #pragma unroll
            for (int o = 0; o < NOUT; ++o) cb = __fmaf_rn(bp[o], fcw[o], cb);
            outv[row] = v + cb;
        }
    } else {
        state[row * 64 + lane] = h;
        #pragma unroll
        for (int j = 0; j < FREQN; ++j) {
            state[65536 + j * 65536 + row * 64 + lane] = Sre[j];
            state[65536 + 655360 + j * 65536 + row * 64 + lane] = Sim[j];
        }
    }
}

// ---------------------------------------------------------------------------
extern "C" void kernel_launch(void* const* d_in, const int* in_sizes, int n_in,
                              void* d_out, int out_size, void* d_ws, size_t ws_size,
                              hipStream_t stream)
{
    const float* g1  = (const float*)d_in[0];
    const float* Wi  = (const float*)d_in[1];
    const float* Ui  = (const float*)d_in[2];
    const float* bi  = (const float*)d_in[3];
    const float* Wst = (const float*)d_in[4];
    const float* Ust = (const float*)d_in[5];
    const float* bst = (const float*)d_in[6];
    const float* Wfr = (const float*)d_in[7];
    const float* Ufq = (const float*)d_in[8];
    const float* bfr = (const float*)d_in[9];
    const float* Wc  = (const float*)d_in[10];
    const float* Uc  = (const float*)d_in[11];
    const float* bc  = (const float*)d_in[12];
    const float* Wo  = (const float*)d_in[13];
    const float* Uo  = (const float*)d_in[14];
    const float* bo  = (const float*)d_in[15];
    const float* Ua  = (const float*)d_in[16];
    const float* ba  = (const float*)d_in[17];
    const float* Wp  = (const float*)d_in[18];
    const float* bp  = (const float*)d_in[19];
    const float* fcw = (const float*)d_in[20];
    const float* fcb = (const float*)d_in[21];
    float* outv = (float*)d_out;

    const size_t stateFloats = 65536 + 2 * 655360;       // h + Sre + Sim
    const size_t csFloats    = TSTEPS * FREQN * 2;
    // pick the largest time-chunk TC whose xproj buffer + state + table fits d_ws
    int TC = 128;
    while (TC > 8 &&
           ((size_t)1024 * TC * XSTRIDE + stateFloats + csFloats) * 4 > ws_size)
        TC >>= 1;
    int tclog = 31 - __builtin_clz((unsigned)TC);
    int nchunks = TSTEPS / TC;

    float*  xproj = (float*)d_ws;
    float*  state = xproj + (size_t)1024 * TC * XSTRIDE;
    float2* csTab = (float2*)(state + stateFloats);

    hipFuncSetAttribute((const void*)rec_kernel,
                        hipFuncAttributeMaxDynamicSharedMemorySize, 68096);

    cstab_kernel<<<(TSTEPS * FREQN + 255) / 256, 256, 0, stream>>>(csTab);

    const int Mt = (1024 * TC) / 128;
    for (int ci = 0; ci < nchunks; ++ci) {
        gemm_xw64<<<dim3(Mt, 4), 256, 0, stream>>>(g1, Wi, Wst, Wc, Wo,
                                                   bi, bst, bc, bo,
                                                   xproj, ci, tclog);
        gemm_xwfre<<<dim3(Mt, 1), 256, 0, stream>>>(g1, Wfr, bfr, xproj, ci, tclog);
        rec_kernel<<<256, 256, 68096, stream>>>(xproj, Ui, Ust, Uc, Uo, Ufq, Ua, ba,
                                                csTab, state, Wp, bp, fcw, fcb, outv,
                                                ci, TC, nchunks);
    }
}

// Round 2
// 719.031 us; speedup vs baseline: 2.5664x; 2.5664x over previous
//
#include <hip/hip_runtime.h>
#include <hip/hip_bf16.h>
#include <cstdint>

#define TSTEPS  128
#define INDIM   256
#define HIDDEN  64
#define FREQN   10
#define NOUT    16
#define XSTRIDE 272   // padded col stride of xproj: [i:0][ste:64][c:128][o:192][fre:256..265]

// ---------------------------------------------------------------------------
// GEMM: xproj[:, seg] = g1row @ W_seg + b_seg   (four 64-col segments)
// ---------------------------------------------------------------------------
__global__ __launch_bounds__(256)
void gemm_xw64(const float* __restrict__ A,
               const float* __restrict__ W0, const float* __restrict__ W1,
               const float* __restrict__ W2, const float* __restrict__ W3,
               const float* __restrict__ b0, const float* __restrict__ b1,
               const float* __restrict__ b2, const float* __restrict__ b3,
               float* __restrict__ outp, int ci, int tclog)
{
    __shared__ float As[32][132];
    __shared__ float Bs[32][68];
    const int tid = threadIdx.x;
    const int bm  = blockIdx.x;
    const float* W; const float* bb;
    switch (blockIdx.y) {
        case 0:  W = W0; bb = b0; break;
        case 1:  W = W1; bb = b1; break;
        case 2:  W = W2; bb = b2; break;
        default: W = W3; bb = b3; break;
    }
    const int col0 = blockIdx.y * 64;
    const int tx = tid & 15, ty = tid >> 4;
    const int lr = tid >> 3, lk4 = (tid & 7) * 4;
    const int tcm = (1 << tclog) - 1;

    float acc[8][4];
    #pragma unroll
    for (int i = 0; i < 8; ++i)
        #pragma unroll
        for (int j = 0; j < 4; ++j) acc[i][j] = 0.f;

    for (int k0 = 0; k0 < INDIM; k0 += 32) {
        #pragma unroll
        for (int p = 0; p < 4; ++p) {
            int r  = lr + p * 32;
            int rp = bm * 128 + r;
            int grow = ((rp >> tclog) << 7) + (ci << tclog) + (rp & tcm);
            float4 v = *reinterpret_cast<const float4*>(A + (size_t)grow * INDIM + k0 + lk4);
            As[lk4 + 0][r] = v.x; As[lk4 + 1][r] = v.y;
            As[lk4 + 2][r] = v.z; As[lk4 + 3][r] = v.w;
        }
        #pragma unroll
        for (int p = 0; p < 2; ++p) {
            int kr = (tid >> 4) + p * 16;
            int c4 = (tid & 15) * 4;
            float4 v = *reinterpret_cast<const float4*>(W + (size_t)(k0 + kr) * 64 + c4);
            *reinterpret_cast<float4*>(&Bs[kr][c4]) = v;
        }
        __syncthreads();
        #pragma unroll
        for (int kk = 0; kk < 32; ++kk) {
            float4 a0 = *reinterpret_cast<const float4*>(&As[kk][ty * 8]);
            float4 a1 = *reinterpret_cast<const float4*>(&As[kk][ty * 8 + 4]);
            float4 b  = *reinterpret_cast<const float4*>(&Bs[kk][tx * 4]);
            float av[8] = {a0.x, a0.y, a0.z, a0.w, a1.x, a1.y, a1.z, a1.w};
            float bv[4] = {b.x, b.y, b.z, b.w};
            #pragma unroll
            for (int i = 0; i < 8; ++i)
                #pragma unroll
                for (int j = 0; j < 4; ++j)
                    acc[i][j] = __fmaf_rn(av[i], bv[j], acc[i][j]);
        }
        __syncthreads();
    }
    #pragma unroll
    for (int i = 0; i < 8; ++i) {
        int rp = bm * 128 + ty * 8 + i;
        #pragma unroll
        for (int j = 0; j < 4; ++j) {
            int c = tx * 4 + j;
            outp[(size_t)rp * XSTRIDE + col0 + c] = acc[i][j] + bb[c];
        }
    }
}

// fre segment: 10 output cols
__global__ __launch_bounds__(256)
void gemm_xwfre(const float* __restrict__ A, const float* __restrict__ W,
                const float* __restrict__ bb, float* __restrict__ outp,
                int ci, int tclog)
{
    __shared__ float As[32][132];
    __shared__ float Bs[32][16];
    const int tid = threadIdx.x;
    const int bm  = blockIdx.x;
    const int tx = tid & 15, ty = tid >> 4;
    const int lr = tid >> 3, lk4 = (tid & 7) * 4;
    const int tcm = (1 << tclog) - 1;

    float acc[8];
    #pragma unroll
    for (int i = 0; i < 8; ++i) acc[i] = 0.f;

    for (int k0 = 0; k0 < INDIM; k0 += 32) {
        #pragma unroll
        for (int p = 0; p < 4; ++p) {
            int r  = lr + p * 32;
            int rp = bm * 128 + r;
            int grow = ((rp >> tclog) << 7) + (ci << tclog) + (rp & tcm);
            float4 v = *reinterpret_cast<const float4*>(A + (size_t)grow * INDIM + k0 + lk4);
            As[lk4 + 0][r] = v.x; As[lk4 + 1][r] = v.y;
            As[lk4 + 2][r] = v.z; As[lk4 + 3][r] = v.w;
        }
        #pragma unroll
        for (int p = 0; p < 2; ++p) {
            int idx = p * 256 + tid;
            int kr = idx >> 4, c = idx & 15;
            Bs[kr][c] = (c < FREQN) ? W[(size_t)(k0 + kr) * FREQN + c] : 0.f;
        }
        __syncthreads();
        #pragma unroll
        for (int kk = 0; kk < 32; ++kk) {
            float4 a0 = *reinterpret_cast<const float4*>(&As[kk][ty * 8]);
            float4 a1 = *reinterpret_cast<const float4*>(&As[kk][ty * 8 + 4]);
            float b = Bs[kk][tx];
            float av[8] = {a0.x, a0.y, a0.z, a0.w, a1.x, a1.y, a1.z, a1.w};
            #pragma unroll
            for (int i = 0; i < 8; ++i) acc[i] = __fmaf_rn(av[i], b, acc[i]);
        }
        __syncthreads();
    }
    if (tx < FREQN) {
        #pragma unroll
        for (int i = 0; i < 8; ++i) {
            int rp = bm * 128 + ty * 8 + i;
            outp[(size_t)rp * XSTRIDE + 256 + tx] = acc[i] + bb[tx];
        }
    }
}

// ---------------------------------------------------------------------------
// cos/sin table (bit-matches reference fp32 rounding order)
// ---------------------------------------------------------------------------
__global__ void cstab_kernel(float2* __restrict__ tab)
{
    int idx = blockIdx.x * 256 + threadIdx.x;
    if (idx >= TSTEPS * FREQN) return;
    int t = idx / FREQN, j = idx - t * FREQN;
    float time = (float)(t + 1);
    float om = (6.28318530717958647692f * time) * ((float)j / 10.0f);
    float s, c;
    sincosf(om, &s, &c);
    tab[idx] = make_float2(c, s);
}

// ---------------------------------------------------------------------------
// Recurrent kernel: one wave per batch row, lane = hidden dim.
// R1 change: k-loop unroll bounded to 8 (was full-64 -> 256 VGPR + scratch
// spills -> 600 MB spill reloads) + launch_bounds(256,1) to permit >256 VGPR
// instead of spilling.
// ---------------------------------------------------------------------------
__device__ __forceinline__ float rdlane(float v, int l) {
    return __int_as_float(__builtin_amdgcn_readlane(__float_as_int(v), l));
}
__device__ __forceinline__ float hsig(float x) {
    return fminf(fmaxf(__fmaf_rn(x, (1.0f / 6.0f), 0.5f), 0.0f), 1.0f);
}
__device__ __forceinline__ float tanh_f(float x) {
    float e = __expf(2.0f * x);
    return 1.0f - 2.0f / (e + 1.0f);
}

__global__ __launch_bounds__(256, 1)
void rec_kernel(const float* __restrict__ xproj,
                const float* __restrict__ Ui, const float* __restrict__ Us,
                const float* __restrict__ Uc, const float* __restrict__ Uo,
                const float* __restrict__ Ufre, const float* __restrict__ Ua,
                const float* __restrict__ ba,
                const float2* __restrict__ csTab,
                float* __restrict__ state,
                const float* __restrict__ Wp, const float* __restrict__ bp,
                const float* __restrict__ fcw, const float* __restrict__ fcb,
                float* __restrict__ outv,
                int ci, int TC, int nchunks)
{
    extern __shared__ float smem[];                 // 4096*4 + 640 floats = 68096 B
    float4* Upk = reinterpret_cast<float4*>(smem);
    float*  Ufr = smem + 16384;
    const int tid = threadIdx.x;

    for (int idx = tid; idx < 4096; idx += 256)
        Upk[idx] = make_float4(Ui[idx], Us[idx], Uc[idx], Uo[idx]);
    for (int idx = tid; idx < 640; idx += 256) Ufr[idx] = Ufre[idx];
    __syncthreads();

    const int lane = tid & 63;
    const int w    = tid >> 6;
    const int row  = blockIdx.x * 4 + w;
    const int jc   = (lane < FREQN) ? lane : (FREQN - 1);

    float h, Sre[FREQN], Sim[FREQN];
    if (ci == 0) {
        h = 0.f;
        #pragma unroll
        for (int j = 0; j < FREQN; ++j) { Sre[j] = 0.f; Sim[j] = 0.f; }
    } else {
        h = state[row * 64 + lane];
        #pragma unroll
        for (int j = 0; j < FREQN; ++j) {
            Sre[j] = state[65536 + j * 65536 + row * 64 + lane];
            Sim[j] = state[65536 + 655360 + j * 65536 + row * 64 + lane];
        }
    }
    const float ba_l = ba[lane];
    float sua[FREQN];
    #pragma unroll
    for (int j = 0; j < FREQN; ++j) sua[j] = Ua[j];

    const float* xbase = xproj + (size_t)row * TC * XSTRIDE;
    float xi = xbase[lane], xs = xbase[64 + lane], xc = xbase[128 + lane];
    float xo = xbase[192 + lane], xf = xbase[256 + jc];
    float2 cv = csTab[(ci * TC) * FREQN + jc];

    for (int tt = 0; tt < TC; ++tt) {
        float cxi = xi, cxs = xs, cxc = xc, cxo = xo, cxf = xf;
        float2 ccv = cv;
        if (tt + 1 < TC) {
            const float* b = xbase + (size_t)(tt + 1) * XSTRIDE;
            xi = b[lane]; xs = b[64 + lane]; xc = b[128 + lane];
            xo = b[192 + lane]; xf = b[256 + jc];
            cv = csTab[(ci * TC + tt + 1) * FREQN + jc];
        }
        float ai = 0.f, as_ = 0.f, ac = 0.f, ao = 0.f, af = 0.f;
        #pragma unroll 8
        for (int k = 0; k < HIDDEN; ++k) {
            float hk = rdlane(h, k);
            float4 u = Upk[k * 64 + lane];
            float uf = Ufr[k * FREQN + jc];
            ai  = __fmaf_rn(hk, u.x, ai);
            as_ = __fmaf_rn(hk, u.y, as_);
            ac  = __fmaf_rn(hk, u.z, ac);
            ao  = __fmaf_rn(hk, u.w, ao);
            af  = __fmaf_rn(hk, uf, af);
        }
        float gi = hsig(cxi + ai);
        float gs = hsig(cxs + as_);
        float gc = gi * tanh_f(cxc + ac);
        float go = hsig(cxo + ao);
        float pf = cxf + af;
        float aacc = 0.f;
        #pragma unroll
        for (int j = 0; j < FREQN; ++j) {
            float fre_j = hsig(rdlane(pf, j));
            float cj = rdlane(ccv.x, j);
            float sj = rdlane(ccv.y, j);
            float fj = gs * fre_j;
            Sre[j] = __fmaf_rn(fj, Sre[j], gc * cj);
            Sim[j] = __fmaf_rn(fj, Sim[j], gc * sj);
            float Aj = __fmaf_rn(Sre[j], Sre[j], Sim[j] * Sim[j]);
            aacc = __fmaf_rn(Aj, sua[j], aacc);
        }
        float ag = tanh_f(aacc + ba_l);
        h = go * ag;
    }

    if (ci == nchunks - 1) {
        float wef = 0.f;
        #pragma unroll
        for (int o = 0; o < NOUT; ++o)
            wef = __fmaf_rn(Wp[lane * NOUT + o], fcw[o], wef);
        float v = h * wef;
        #pragma unroll
        for (int off = 32; off > 0; off >>= 1) v += __shfl_xor(v, off, 64);
        if (lane == 0) {
            float cb = fcb[0];
            #pragma unroll
            for (int o = 0; o < NOUT; ++o) cb = __fmaf_rn(bp[o], fcw[o], cb);
            outv[row] = v + cb;
        }
    } else {
        state[row * 64 + lane] = h;
        #pragma unroll
        for (int j = 0; j < FREQN; ++j) {
            state[65536 + j * 65536 + row * 64 + lane] = Sre[j];
            state[65536 + 655360 + j * 65536 + row * 64 + lane] = Sim[j];
        }
    }
}

// ---------------------------------------------------------------------------
extern "C" void kernel_launch(void* const* d_in, const int* in_sizes, int n_in,
                              void* d_out, int out_size, void* d_ws, size_t ws_size,
                              hipStream_t stream)
{
    const float* g1  = (const float*)d_in[0];
    const float* Wi  = (const float*)d_in[1];
    const float* Ui  = (const float*)d_in[2];
    const float* bi  = (const float*)d_in[3];
    const float* Wst = (const float*)d_in[4];
    const float* Ust = (const float*)d_in[5];
    const float* bst = (const float*)d_in[6];
    const float* Wfr = (const float*)d_in[7];
    const float* Ufq = (const float*)d_in[8];
    const float* bfr = (const float*)d_in[9];
    const float* Wc  = (const float*)d_in[10];
    const float* Uc  = (const float*)d_in[11];
    const float* bc  = (const float*)d_in[12];
    const float* Wo  = (const float*)d_in[13];
    const float* Uo  = (const float*)d_in[14];
    const float* bo  = (const float*)d_in[15];
    const float* Ua  = (const float*)d_in[16];
    const float* ba  = (const float*)d_in[17];
    const float* Wp  = (const float*)d_in[18];
    const float* bp  = (const float*)d_in[19];
    const float* fcw = (const float*)d_in[20];
    const float* fcb = (const float*)d_in[21];
    float* outv = (float*)d_out;

    const size_t stateFloats = 65536 + 2 * 655360;
    const size_t csFloats    = TSTEPS * FREQN * 2;
    int TC = 128;
    while (TC > 8 &&
           ((size_t)1024 * TC * XSTRIDE + stateFloats + csFloats) * 4 > ws_size)
        TC >>= 1;
    int tclog = 31 - __builtin_clz((unsigned)TC);
    int nchunks = TSTEPS / TC;

    float*  xproj = (float*)d_ws;
    float*  state = xproj + (size_t)1024 * TC * XSTRIDE;
    float2* csTab = (float2*)(state + stateFloats);

    hipFuncSetAttribute((const void*)rec_kernel,
                        hipFuncAttributeMaxDynamicSharedMemorySize, 68096);

    cstab_kernel<<<(TSTEPS * FREQN + 255) / 256, 256, 0, stream>>>(csTab);

    const int Mt = (1024 * TC) / 128;
    for (int ci = 0; ci < nchunks; ++ci) {
        gemm_xw64<<<dim3(Mt, 4), 256, 0, stream>>>(g1, Wi, Wst, Wc, Wo,
                                                   bi, bst, bc, bo,
                                                   xproj, ci, tclog);
        gemm_xwfre<<<dim3(Mt, 1), 256, 0, stream>>>(g1, Wfr, bfr, xproj, ci, tclog);
        rec_kernel<<<256, 256, 68096, stream>>>(xproj, Ui, Ust, Uc, Uo, Ufq, Ua, ba,
                                                csTab, state, Wp, bp, fcw, fcb, outv,
                                                ci, TC, nchunks);
    }
}

// Round 4
// 554.136 us; speedup vs baseline: 3.3301x; 1.2976x over previous
//
#include <hip/hip_runtime.h>
#include <cstdint>

#define TSTEPS  128
#define INDIM   256
#define HIDDEN  64
#define FREQN   10
#define NOUT    16
#define XSTRIDE 272   // xproj cols: [i:0][ste:64][c:128][o:192][fre:256..265][pad..271]
#define NTILE   17    // 272/16 N-tiles

typedef __attribute__((ext_vector_type(8))) short bf16x8;
typedef __attribute__((ext_vector_type(4))) float f32x4;

__device__ __forceinline__ unsigned short bf16h(float x) {
    unsigned u = __float_as_uint(x);
    return (unsigned short)((u + 0x7FFFu + ((u >> 16) & 1u)) >> 16);
}
__device__ __forceinline__ float rdlane(float v, int l) {
    return __int_as_float(__builtin_amdgcn_readlane(__float_as_int(v), l));
}
__device__ __forceinline__ float hsig(float x) {
    return fminf(fmaxf(__fmaf_rn(x, (1.0f / 6.0f), 0.5f), 0.0f), 1.0f);
}
__device__ __forceinline__ float tanh_f(float x) {
    float e = __expf(2.0f * x);
    return 1.0f - 2.0f / (e + 1.0f);
}

// ---------------------------------------------------------------------------
// Pack W = [Wi|Wst|Wc|Wo|Wfre|0pad] (256 x 272) into split-bf16 MFMA B-fragments.
// Fragment (s,t): lane l supplies B[k = 32s + (l>>4)*8 + i][n = 16t + (l&15)],
// i=0..7, as 8 hi ushorts then 8 lo ushorts. Same k-slot map used for A -> any
// k-permutation error cancels in the MFMA contraction.
// ---------------------------------------------------------------------------
__global__ void pack_w(const float* __restrict__ Wi, const float* __restrict__ Wst,
                       const float* __restrict__ Wc, const float* __restrict__ Wo,
                       const float* __restrict__ Wfr,
                       const float* __restrict__ bi, const float* __restrict__ bst,
                       const float* __restrict__ bc, const float* __restrict__ bo,
                       const float* __restrict__ bfr,
                       unsigned short* __restrict__ Wpk, float* __restrict__ bias)
{
    int idx = blockIdx.x * 256 + threadIdx.x;
    if (idx < 8 * NTILE * 64) {
        int l = idx & 63;
        int t = (idx >> 6) % NTILE;
        int s = idx / (64 * NTILE);
        int n = t * 16 + (l & 15);
        unsigned short* dst = Wpk + (size_t)idx * 16;
        #pragma unroll
        for (int i = 0; i < 8; ++i) {
            int k = s * 32 + (l >> 4) * 8 + i;
            float v;
            if      (n < 64)  v = Wi [k * 64 + n];
            else if (n < 128) v = Wst[k * 64 + (n - 64)];
            else if (n < 192) v = Wc [k * 64 + (n - 128)];
            else if (n < 256) v = Wo [k * 64 + (n - 192)];
            else if (n < 266) v = Wfr[k * 10 + (n - 256)];
            else              v = 0.f;
            unsigned short h = bf16h(v);
            float hf = __uint_as_float((unsigned)h << 16);
            dst[i]     = h;
            dst[8 + i] = bf16h(v - hf);
        }
    } else if (idx < 8 * NTILE * 64 + XSTRIDE) {
        int n = idx - 8 * NTILE * 64;
        float b;
        if      (n < 64)  b = bi [n];
        else if (n < 128) b = bst[n - 64];
        else if (n < 192) b = bc [n - 128];
        else if (n < 256) b = bo [n - 192];
        else if (n < 266) b = bfr[n - 256];
        else              b = 0.f;
        bias[n] = b;
    }
}

// ---------------------------------------------------------------------------
// Split-bf16 MFMA GEMM: xproj = g1 @ [W...] + bias.  Wave: 32 rows x 272 cols,
// K=256. 3 MFMAs (hh, hl, lh) per logical tile-product ~ fp32 precision.
// ---------------------------------------------------------------------------
__global__ __launch_bounds__(256, 2)
void gemm_mfma(const float* __restrict__ A, const unsigned short* __restrict__ Wpk,
               const float* __restrict__ bias, float* __restrict__ outp,
               int ci, int tclog)
{
    const int tid = threadIdx.x;
    const int w   = tid >> 6, l = tid & 63;
    const int l15 = l & 15,  lg = l >> 4;
    const int tcm = (1 << tclog) - 1;
    const int rbase = blockIdx.x * 128 + w * 32;   // chunk-local row base

    f32x4 acc[2][NTILE];
    #pragma unroll
    for (int rt = 0; rt < 2; ++rt)
        #pragma unroll
        for (int t = 0; t < NTILE; ++t) acc[rt][t] = (f32x4){0.f, 0.f, 0.f, 0.f};

    #pragma unroll
    for (int s = 0; s < 8; ++s) {
        bf16x8 ahi[2], alo[2];
        #pragma unroll
        for (int rt = 0; rt < 2; ++rt) {
            int rp   = rbase + rt * 16 + l15;
            int grow = ((rp >> tclog) << 7) + (ci << tclog) + (rp & tcm);
            const float* ap = A + (size_t)grow * INDIM + s * 32 + lg * 8;
            float4 a0 = *reinterpret_cast<const float4*>(ap);
            float4 a1 = *reinterpret_cast<const float4*>(ap + 4);
            float av[8] = {a0.x, a0.y, a0.z, a0.w, a1.x, a1.y, a1.z, a1.w};
            union { bf16x8 v; unsigned short u[8]; } H, L;
            #pragma unroll
            for (int i = 0; i < 8; ++i) {
                unsigned short h = bf16h(av[i]);
                H.u[i] = h;
                L.u[i] = bf16h(av[i] - __uint_as_float((unsigned)h << 16));
            }
            ahi[rt] = H.v; alo[rt] = L.v;
        }
        #pragma unroll
        for (int t = 0; t < NTILE; ++t) {
            const bf16x8* bp =
                reinterpret_cast<const bf16x8*>(Wpk + ((size_t)(s * NTILE + t) * 64 + l) * 16);
            bf16x8 bhi = bp[0], blo = bp[1];
            #pragma unroll
            for (int rt = 0; rt < 2; ++rt) {
                acc[rt][t] = __builtin_amdgcn_mfma_f32_16x16x32_bf16(ahi[rt], bhi, acc[rt][t], 0, 0, 0);
                acc[rt][t] = __builtin_amdgcn_mfma_f32_16x16x32_bf16(ahi[rt], blo, acc[rt][t], 0, 0, 0);
                acc[rt][t] = __builtin_amdgcn_mfma_f32_16x16x32_bf16(alo[rt], bhi, acc[rt][t], 0, 0, 0);
            }
        }
    }
    // C/D layout (verified): col = lane&15, row = (lane>>4)*4 + reg
    #pragma unroll
    for (int t = 0; t < NTILE; ++t) {
        float bv = bias[t * 16 + l15];
        #pragma unroll
        for (int rt = 0; rt < 2; ++rt) {
            int rp0 = rbase + rt * 16 + lg * 4;
            #pragma unroll
            for (int r = 0; r < 4; ++r)
                outp[(size_t)(rp0 + r) * XSTRIDE + t * 16 + l15] = acc[rt][t][r] + bv;
        }
    }
}

// ---------------------------------------------------------------------------
// cos/sin table (bit-matches reference fp32 rounding order)
// ---------------------------------------------------------------------------
__global__ void cstab_kernel(float2* __restrict__ tab)
{
    int idx = blockIdx.x * 256 + threadIdx.x;
    if (idx >= TSTEPS * FREQN) return;
    int t = idx / FREQN, j = idx - t * FREQN;
    float time = (float)(t + 1);
    float om = (6.28318530717958647692f * time) * ((float)j / 10.0f);
    float s, c;
    sincosf(om, &s, &c);
    tab[idx] = make_float2(c, s);
}

// ---------------------------------------------------------------------------
// Recurrent kernel R3: 1 block = 1 row = 4 waves, k-sliced 16 each.
// U lives in VGPRs (64 per lane) -- no LDS-U re-read (R2's 320KB/CU/step).
// LDS only for 4.5KB/step partial exchange + h broadcast.
// ---------------------------------------------------------------------------
__global__ __launch_bounds__(256, 3)
void rec_kernel(const float* __restrict__ xproj,
                const float* __restrict__ Ui, const float* __restrict__ Us,
                const float* __restrict__ Uc, const float* __restrict__ Uo,
                const float* __restrict__ Ufre, const float* __restrict__ Ua,
                const float* __restrict__ ba,
                const float2* __restrict__ csTab,
                float* __restrict__ state,
                const float* __restrict__ Wp, const float* __restrict__ bp,
                const float* __restrict__ fcw, const float* __restrict__ fcb,
                float* __restrict__ outv,
                int ci, int TC, int nchunks)
{
    __shared__ f32x4 pg[4][64];
    __shared__ float pf_[4][16];
    __shared__ float hlds[64];
    const int tid  = threadIdx.x;
    const int lane = tid & 63, w = tid >> 6;
    const int row  = blockIdx.x;
    const int k0   = w * 16;
    const int jc   = (lane < FREQN) ? lane : (FREQN - 1);

    // per-lane U slice: Ur[i] = {Ui,Us,Uc,Uo}[k0+i][lane], Uf[i] = Ufre[k0+i][jc]
    float4 Ur[16]; float Uf[16];
    #pragma unroll
    for (int i = 0; i < 16; ++i) {
        int k = k0 + i;
        Ur[i] = make_float4(Ui[k * 64 + lane], Us[k * 64 + lane],
                            Uc[k * 64 + lane], Uo[k * 64 + lane]);
        Uf[i] = Ufre[k * FREQN + jc];
    }

    float hv;
    float Sre[FREQN], Sim[FREQN];
    if (ci == 0) {
        hv = 0.f;
        #pragma unroll
        for (int j = 0; j < FREQN; ++j) { Sre[j] = 0.f; Sim[j] = 0.f; }
    } else {
        hv = state[row * 64 + lane];
        if (w == 0) {
            #pragma unroll
            for (int j = 0; j < FREQN; ++j) {
                Sre[j] = state[65536 + j * 65536 + row * 64 + lane];
                Sim[j] = state[65536 + 655360 + j * 65536 + row * 64 + lane];
            }
        }
    }

    const float ba_l = ba[lane];
    float sua[FREQN];
    #pragma unroll
    for (int j = 0; j < FREQN; ++j) sua[j] = Ua[j];   // uniform -> SGPR

    const float* xb = xproj + (size_t)row * TC * XSTRIDE;
    float xi = 0.f, xs = 0.f, xc = 0.f, xo = 0.f, xf = 0.f;
    float2 cv = make_float2(0.f, 0.f);
    if (w == 0) {
        xi = xb[lane]; xs = xb[64 + lane]; xc = xb[128 + lane];
        xo = xb[192 + lane]; xf = xb[256 + jc];
        cv = csTab[(ci * TC) * FREQN + jc];
    }

    for (int tt = 0; tt < TC; ++tt) {
        // --- all waves: partial matvec over own 16-k slice ---
        float ai = 0.f, as_ = 0.f, ac = 0.f, ao = 0.f, af = 0.f;
        #pragma unroll
        for (int i = 0; i < 16; ++i) {
            float hk = rdlane(hv, k0 + i);           // wave-uniform lane index
            ai  = __fmaf_rn(hk, Ur[i].x, ai);
            as_ = __fmaf_rn(hk, Ur[i].y, as_);
            ac  = __fmaf_rn(hk, Ur[i].z, ac);
            ao  = __fmaf_rn(hk, Ur[i].w, ao);
            af  = __fmaf_rn(hk, Uf[i],  af);
        }
        pg[w][lane] = (f32x4){ai, as_, ac, ao};
        if (lane < FREQN) pf_[w][lane] = af;
        __syncthreads();

        // --- wave 0: reduce + gates + SM update + new h ---
        if (w == 0) {
            f32x4 q0 = pg[0][lane], q1 = pg[1][lane], q2 = pg[2][lane], q3 = pg[3][lane];
            float si = (q0[0] + q1[0]) + (q2[0] + q3[0]);
            float ss = (q0[1] + q1[1]) + (q2[1] + q3[1]);
            float sc = (q0[2] + q1[2]) + (q2[2] + q3[2]);
            float so = (q0[3] + q1[3]) + (q2[3] + q3[3]);
            float pfr = (pf_[0][jc] + pf_[1][jc]) + (pf_[2][jc] + pf_[3][jc]);
            float cxi = xi, cxs = xs, cxc = xc, cxo = xo, cxf = xf;
            float2 ccv = cv;
            if (tt + 1 < TC) {                       // prefetch next step
                const float* b2 = xb + (size_t)(tt + 1) * XSTRIDE;
                xi = b2[lane]; xs = b2[64 + lane]; xc = b2[128 + lane];
                xo = b2[192 + lane]; xf = b2[256 + jc];
                cv = csTab[(ci * TC + tt + 1) * FREQN + jc];
            }
            float gi = hsig(cxi + si);
            float gs = hsig(cxs + ss);
            float go = hsig(cxo + so);
            float gc = gi * tanh_f(cxc + sc);
            float pfull = cxf + pfr;
            float aacc = 0.f;
            #pragma unroll
            for (int j = 0; j < FREQN; ++j) {
                float fre = hsig(rdlane(pfull, j));
                float cj = rdlane(ccv.x, j);
                float sj = rdlane(ccv.y, j);
                float fj = gs * fre;
                Sre[j] = __fmaf_rn(fj, Sre[j], gc * cj);
                Sim[j] = __fmaf_rn(fj, Sim[j], gc * sj);
                float Aj = __fmaf_rn(Sre[j], Sre[j], Sim[j] * Sim[j]);
                aacc = __fmaf_rn(Aj, sua[j], aacc);
            }
            hlds[lane] = go * tanh_f(aacc + ba_l);
        }
        __syncthreads();
        hv = hlds[lane];
    }

    if (ci == nchunks - 1) {
        if (w == 0) {
            float wef = 0.f;
            #pragma unroll
            for (int o = 0; o < NOUT; ++o)
                wef = __fmaf_rn(Wp[lane * NOUT + o], fcw[o], wef);
            float v = hv * wef;
            #pragma unroll
            for (int off = 32; off > 0; off >>= 1) v += __shfl_xor(v, off, 64);
            if (lane == 0) {
                float cb = fcb[0];
                #pragma unroll
                for (int o = 0; o < NOUT; ++o) cb = __fmaf_rn(bp[o], fcw[o], cb);
                outv[row] = v + cb;
            }
        }
    } else if (w == 0) {
        state[row * 64 + lane] = hv;
        #pragma unroll
        for (int j = 0; j < FREQN; ++j) {
            state[65536 + j * 65536 + row * 64 + lane] = Sre[j];
            state[65536 + 655360 + j * 65536 + row * 64 + lane] = Sim[j];
        }
    }
}

// ---------------------------------------------------------------------------
extern "C" void kernel_launch(void* const* d_in, const int* in_sizes, int n_in,
                              void* d_out, int out_size, void* d_ws, size_t ws_size,
                              hipStream_t stream)
{
    const float* g1  = (const float*)d_in[0];
    const float* Wi  = (const float*)d_in[1];
    const float* Ui  = (const float*)d_in[2];
    const float* bi  = (const float*)d_in[3];
    const float* Wst = (const float*)d_in[4];
    const float* Ust = (const float*)d_in[5];
    const float* bst = (const float*)d_in[6];
    const float* Wfr = (const float*)d_in[7];
    const float* Ufq = (const float*)d_in[8];
    const float* bfr = (const float*)d_in[9];
    const float* Wc  = (const float*)d_in[10];
    const float* Uc  = (const float*)d_in[11];
    const float* bc  = (const float*)d_in[12];
    const float* Wo  = (const float*)d_in[13];
    const float* Uo  = (const float*)d_in[14];
    const float* bo  = (const float*)d_in[15];
    const float* Ua  = (const float*)d_in[16];
    const float* ba  = (const float*)d_in[17];
    const float* Wp  = (const float*)d_in[18];
    const float* bp  = (const float*)d_in[19];
    const float* fcw = (const float*)d_in[20];
    const float* fcb = (const float*)d_in[21];
    float* outv = (float*)d_out;

    const size_t stateFloats = 65536 + 2 * 655360;          // 1,376,256
    const size_t csFloats    = TSTEPS * FREQN * 2;          // 2,560
    const size_t wpkShorts   = (size_t)8 * NTILE * 64 * 16; // 139,264
    int TC = 128;
    while (TC > 8 &&
           ((size_t)1024 * TC * XSTRIDE + stateFloats + csFloats + XSTRIDE) * 4
               + wpkShorts * 2 > ws_size)
        TC >>= 1;
    int tclog = 31 - __builtin_clz((unsigned)TC);
    int nchunks = TSTEPS / TC;

    float*  xproj = (float*)d_ws;
    float*  state = xproj + (size_t)1024 * TC * XSTRIDE;
    float2* csTab = (float2*)(state + stateFloats);
    float*  bias  = (float*)(csTab + TSTEPS * FREQN);
    unsigned short* Wpk = (unsigned short*)(bias + XSTRIDE);

    pack_w<<<36, 256, 0, stream>>>(Wi, Wst, Wc, Wo, Wfr, bi, bst, bc, bo, bfr, Wpk, bias);
    cstab_kernel<<<(TSTEPS * FREQN + 255) / 256, 256, 0, stream>>>(csTab);

    const int Mt = (1024 * TC) / 128;
    for (int ci = 0; ci < nchunks; ++ci) {
        gemm_mfma<<<Mt, 256, 0, stream>>>(g1, Wpk, bias, xproj, ci, tclog);
        rec_kernel<<<1024, 256, 0, stream>>>(xproj, Ui, Ust, Uc, Uo, Ufq, Ua, ba,
                                             csTab, state, Wp, bp, fcw, fcb, outv,
                                             ci, TC, nchunks);
    }
}